// Round 3
// baseline (2961.234 us; speedup 1.0000x reference)
//
#include <hip/hip_runtime.h>
#include <math.h>
#include <float.h>

#define B_   16
#define N_   4096
#define CIN  3
#define COUT 64
#define KNN  20
#define EPS_ 1e-5

// ---------------------------------------------------------------------------
// Workspace layout:
//   [0,   216): double stats[27]    (Sum e[6], Sum e e^T upper-tri[21])
//   [256, 768): float scale[64], shift[64]
//   [1024, 1024 + B*N*KNN*4): int idx[B*N*KNN]
// ---------------------------------------------------------------------------

// ===========================================================================
// Kernel 1: exact-match KNN (top-20 smallest d, jax top_k semantics) + stats.
//
// Evidence from rounds 1-2: the np reference computes d in fp32 EXPANSION
// form (sq_i + sq_j - 2*dot) — fp64-exact ranking mismatched (r2, 0.273), so
// we must replicate fp32 rounding bit-for-bit, including:
//   * sequential accumulation (m0+m1)+m2 for dot and sq (no fma contraction
//     -> __fmul_rn/__fadd_rn intrinsics)
//   * (sq_i + sq_j) - 2*dot association order
//   * tie handling: fp32 equal distances at the heap boundary DO occur;
//     top_k keeps the LOWEST index among equals. Acceptance: strict d<worst
//     (ascending-j scan). Eviction victim: lexicographic max by
//     (value, point-index) — round-0 picked first max SLOT, which sometimes
//     evicted the lower index of an equal pair (the round-0 0.318 failure).
// One block = 256 rows of one batch; all 4096 points of the batch in LDS.
// ===========================================================================
__global__ __launch_bounds__(256) void knn_stats_kernel(
    const float* __restrict__ x, int* __restrict__ idx_out,
    double* __restrict__ stats)
{
    __shared__ float4 pts[N_];   // {x0, x1, x2, |x|^2}  = 64 KB (static LDS cap)

    const int b   = blockIdx.y;
    const int tid = threadIdx.x;
    const float* xb = x + (size_t)b * N_ * CIN;

    for (int p = tid; p < N_; p += 256) {
        float v0 = xb[p * 3 + 0], v1 = xb[p * 3 + 1], v2 = xb[p * 3 + 2];
        float sq = __fadd_rn(__fadd_rn(__fmul_rn(v0, v0), __fmul_rn(v1, v1)),
                             __fmul_rn(v2, v2));
        pts[p] = make_float4(v0, v1, v2, sq);
    }
    __syncthreads();

    const int il = blockIdx.x * 256 + tid;            // row within batch
    const float4 xi = pts[il];
    const float sqi = xi.w;

    // register-resident top-20 (static indexing only -> VGPRs)
    float bd[KNN]; int bi[KNN];
#pragma unroll
    for (int k = 0; k < KNN; ++k) { bd[k] = INFINITY; bi[k] = 0; }
    float worst = INFINITY; int wslot = 0;

#pragma unroll 4
    for (int j = 0; j < N_; ++j) {
        float4 p = pts[j];                            // uniform addr -> broadcast
        float dot = __fadd_rn(__fadd_rn(__fmul_rn(xi.x, p.x),
                                        __fmul_rn(xi.y, p.y)),
                              __fmul_rn(xi.z, p.z));
        float d = __fsub_rn(__fadd_rn(sqi, p.w), __fmul_rn(2.0f, dot));
        if (d < worst) {                              // strict < (ascending j)
#pragma unroll
            for (int k = 0; k < KNN; ++k)
                if (k == wslot) { bd[k] = d; bi[k] = j; }
            // victim = lexicographic max by (value, point index):
            // among equal values evict the HIGHEST index (top_k keeps lowest)
            float w = -INFINITY; int wi = -1; int sl = 0;
#pragma unroll
            for (int k = 0; k < KNN; ++k) {
                bool better = (bd[k] > w) || (bd[k] == w && bi[k] > wi);
                if (better) { w = bd[k]; wi = bi[k]; sl = k; }
            }
            worst = w; wslot = sl;
        }
    }

    const long long row = (long long)b * N_ + il;
#pragma unroll
    for (int k = 0; k < KNN; ++k) idx_out[row * KNN + k] = bi[k];

    // --- BN statistics: Sum e (6) and Sum e e^T (upper triangle, 21) ---
    float acc[27];
#pragma unroll
    for (int t = 0; t < 27; ++t) acc[t] = 0.0f;
#pragma unroll
    for (int k = 0; k < KNN; ++k) {
        float4 pj = pts[bi[k]];
        float e[6] = { xi.x, xi.y, xi.z,
                       pj.x - xi.x, pj.y - xi.y, pj.z - xi.z };
        int t = 6;
#pragma unroll
        for (int a = 0; a < 6; ++a) {
            acc[a] += e[a];
#pragma unroll
            for (int bb = a; bb < 6; ++bb) acc[t++] += e[a] * e[bb];
        }
    }
    // wave reduce (64 lanes), then one fp64 atomic per wave per stat
#pragma unroll
    for (int t = 0; t < 27; ++t) {
        float v = acc[t];
        v += __shfl_down(v, 32); v += __shfl_down(v, 16);
        v += __shfl_down(v, 8);  v += __shfl_down(v, 4);
        v += __shfl_down(v, 2);  v += __shfl_down(v, 1);
        acc[t] = v;
    }
    if ((tid & 63) == 0) {
#pragma unroll
        for (int t = 0; t < 27; ++t) atomicAdd(&stats[t], (double)acc[t]);
    }
}

// ===========================================================================
// Kernel 2: fold stats -> per-channel scale/shift (fp64, 64 threads)
// ===========================================================================
__global__ void bn_prep_kernel(
    const double* __restrict__ stats,
    const float* __restrict__ w1, const float* __restrict__ b1,
    const float* __restrict__ gamma, const float* __restrict__ beta,
    float* __restrict__ scale_shift)
{
    const int c = threadIdx.x;
    double s[6], S[6][6];
#pragma unroll
    for (int a = 0; a < 6; ++a) s[a] = stats[a];
    int t = 6;
#pragma unroll
    for (int a = 0; a < 6; ++a)
#pragma unroll
        for (int bb = a; bb < 6; ++bb) { S[a][bb] = stats[t]; S[bb][a] = stats[t]; ++t; }

    const double M = (double)B_ * N_ * KNN;
    double wc[6];
#pragma unroll
    for (int j = 0; j < 6; ++j) wc[j] = (double)w1[j * COUT + c];
    const double b1c = (double)b1[c];

    double sw = 0.0;
#pragma unroll
    for (int j = 0; j < 6; ++j) sw += s[j] * wc[j];
    double mean = sw / M + b1c;

    double q = 0.0;
#pragma unroll
    for (int a = 0; a < 6; ++a)
#pragma unroll
        for (int bb = 0; bb < 6; ++bb) q += S[a][bb] * wc[a] * wc[bb];
    double ex2 = (q + 2.0 * b1c * sw) / M + b1c * b1c;
    double var = ex2 - mean * mean;

    double sc = (double)gamma[c] / sqrt(var + (double)EPS_);
    double sh = (double)beta[c] - mean * sc;
    scale_shift[c]        = (float)sc;
    scale_shift[COUT + c] = (float)sh;
}

// ===========================================================================
// Kernel 3: fused edge-feature -> lin1 -> BN -> ReLU -> lin2 -> max over K
// One wave per point row; lane = output channel. h never hits HBM.
// ===========================================================================
__global__ __launch_bounds__(256) void mlp_max_kernel(
    const float* __restrict__ x, const int* __restrict__ idx,
    const float* __restrict__ w1, const float* __restrict__ b1,
    const float* __restrict__ scale_shift,
    const float* __restrict__ w2, const float* __restrict__ b2,
    float* __restrict__ out)
{
    __shared__ __align__(16) float h1[4][KNN * COUT];   // 20 KB

    const int tid = threadIdx.x;
    const int wv  = tid >> 6;
    const int c   = tid & 63;
    const int row = blockIdx.x * 4 + wv;                // 0 .. B*N-1
    const int b   = row >> 12;

    float w1c[6];
#pragma unroll
    for (int j = 0; j < 6; ++j) w1c[j] = w1[j * COUT + c];
    const float b1c = b1[c];
    const float sc  = scale_shift[c];
    const float sh  = scale_shift[COUT + c];
    const float b2c = b2[c];
    float w2c[COUT];
#pragma unroll
    for (int d = 0; d < COUT; ++d) w2c[d] = w2[d * COUT + c];

    const float xi0 = x[row * 3 + 0];
    const float xi1 = x[row * 3 + 1];
    const float xi2 = x[row * 3 + 2];

    // phase 1: h1[k][c] = relu(scale*(e . w1col_c + b1_c) + shift)
#pragma unroll
    for (int k = 0; k < KNN; ++k) {
        int j = idx[row * KNN + k];                     // wave-uniform load
        const float* pj = x + ((size_t)b * N_ + j) * 3;
        float e3 = pj[0] - xi0, e4 = pj[1] - xi1, e5 = pj[2] - xi2;
        float h = b1c;
        h = fmaf(xi0, w1c[0], h); h = fmaf(xi1, w1c[1], h);
        h = fmaf(xi2, w1c[2], h); h = fmaf(e3,  w1c[3], h);
        h = fmaf(e4,  w1c[4], h); h = fmaf(e5,  w1c[5], h);
        h = fmaf(h, sc, sh);
        h1[wv][k * COUT + c] = fmaxf(h, 0.0f);
    }
    __syncthreads();

    // phase 2: out[c] = max_k ( h1[k][:] . w2col_c + b2_c )
    float mx = -INFINITY;
    for (int k = 0; k < KNN; ++k) {
        float a = b2c;
#pragma unroll
        for (int d4 = 0; d4 < COUT / 4; ++d4) {
            float4 hv = *(const float4*)&h1[wv][k * COUT + d4 * 4];  // broadcast
            a = fmaf(hv.x, w2c[d4 * 4 + 0], a);
            a = fmaf(hv.y, w2c[d4 * 4 + 1], a);
            a = fmaf(hv.z, w2c[d4 * 4 + 2], a);
            a = fmaf(hv.w, w2c[d4 * 4 + 3], a);
        }
        mx = fmaxf(mx, a);
    }
    out[(size_t)row * COUT + c] = mx;
}

// ===========================================================================
extern "C" void kernel_launch(void* const* d_in, const int* in_sizes, int n_in,
                              void* d_out, int out_size, void* d_ws, size_t ws_size,
                              hipStream_t stream)
{
    const float* x     = (const float*)d_in[0];
    // d_in[1] = batch vector (implied by layout, unused)
    const float* w1    = (const float*)d_in[2];
    const float* b1    = (const float*)d_in[3];
    const float* gamma = (const float*)d_in[4];
    const float* beta  = (const float*)d_in[5];
    const float* w2    = (const float*)d_in[6];
    const float* b2    = (const float*)d_in[7];
    float* out = (float*)d_out;

    char*   ws          = (char*)d_ws;
    double* stats       = (double*)ws;
    float*  scale_shift = (float*)(ws + 256);
    int*    idx         = (int*)(ws + 1024);

    hipMemsetAsync(stats, 0, 27 * sizeof(double), stream);
    knn_stats_kernel<<<dim3(16, 16), 256, 0, stream>>>(x, idx, stats);
    bn_prep_kernel<<<1, COUT, 0, stream>>>(stats, w1, b1, gamma, beta, scale_shift);
    mlp_max_kernel<<<(B_ * N_) / 4, 256, 0, stream>>>(x, idx, w1, b1, scale_shift,
                                                      w2, b2, out);
}

// Round 4
// 1134.243 us; speedup vs baseline: 2.6108x; 2.6108x over previous
//
#include <hip/hip_runtime.h>
#include <math.h>
#include <float.h>

#define B_   16
#define N_   4096
#define CIN  3
#define COUT 64
#define KNN  20
#define EPS_ 1e-5

// ---------------------------------------------------------------------------
// Workspace layout:
//   [0,   216): double stats[27]    (Sum e[6], Sum e e^T upper-tri[21])
//   [256, 768): float scale[64], shift[64]
//   [1024, 1024 + B*N*KNN*4): int idx[B*N*KNN]           (5242880 B)
//   [5243904, +B*N*4): int perm[B*N]  (Morton row order)  (262144 B)
// ---------------------------------------------------------------------------

// ===========================================================================
// Kernel 0: per-batch Morton sort of point indices.
// PERFORMANCE ONLY: lanes in a KNN wave get spatially adjacent query rows so
// their top-20 insert events correlate -> wave-union divergence drops.
// Any permutation is correctness-neutral; bitonic CE networks preserve the
// permutation property even if the comparator ordering were wrong.
// ===========================================================================
__device__ __forceinline__ unsigned expand10(unsigned v) {
    v = (v | (v << 16)) & 0x030000FFu;
    v = (v | (v << 8))  & 0x0300F00Fu;
    v = (v | (v << 4))  & 0x030C30C3u;
    v = (v | (v << 2))  & 0x09249249u;
    return v;
}
__device__ __forceinline__ unsigned quant10(float v) {
    int q = (int)((v + 4.0f) * 128.0f);
    return (unsigned)min(1023, max(0, q));
}

__global__ __launch_bounds__(1024) void morton_sort_kernel(
    const float* __restrict__ x, int* __restrict__ perm)
{
    __shared__ unsigned long long keys[N_];   // 32 KB
    const int b   = blockIdx.x;
    const int tid = threadIdx.x;
    const float* xb = x + (size_t)b * N_ * CIN;

    for (int p = tid; p < N_; p += 1024) {
        float v0 = xb[p * 3 + 0], v1 = xb[p * 3 + 1], v2 = xb[p * 3 + 2];
        unsigned m = (expand10(quant10(v0)) << 2) |
                     (expand10(quant10(v1)) << 1) |
                      expand10(quant10(v2));
        keys[p] = ((unsigned long long)m << 32) | (unsigned)p;
    }
    __syncthreads();

    for (int k = 2; k <= N_; k <<= 1) {
        for (int jj = k >> 1; jj > 0; jj >>= 1) {
            for (int t = tid; t < N_ / 2; t += 1024) {
                int i = ((t & ~(jj - 1)) << 1) | (t & (jj - 1));
                int p = i | jj;
                bool up = ((i & k) == 0);
                unsigned long long a = keys[i], c = keys[p];
                bool sw = up ? (a > c) : (a < c);
                if (sw) { keys[i] = c; keys[p] = a; }
            }
            __syncthreads();
        }
    }
    for (int p = tid; p < N_; p += 1024)
        perm[b * N_ + p] = (int)(keys[p] & 0xFFFFu);
}

// ===========================================================================
// Kernel 1: exact-match KNN (top-20, jax top_k semantics) + BN stats.
// Distance: fp32 EXPANSION form, bit-identical to np ref (verified round 3):
//   sq = (x*x + y*y) + z*z ;  d = (sq_i + sq_j) - 2*((xx+yy)+zz)
// Selection state: 20 u64 keys  (sortable_fp32(d) << 32) | j.
// "20 smallest u64 keys" == top_k with lowest-index tie-break, exactly.
// (-0.0 cannot occur: fsub(a,b) in RN yields +0 for a==b.)
// ===========================================================================
__global__ __launch_bounds__(256) void knn_stats_kernel(
    const float* __restrict__ x, const int* __restrict__ perm,
    int* __restrict__ idx_out, double* __restrict__ stats)
{
    __shared__ float4 pts[N_];   // {x0,x1,x2,|x|^2} = 64 KB (static LDS cap)

    const int b   = blockIdx.y;
    const int tid = threadIdx.x;
    const float* xb = x + (size_t)b * N_ * CIN;

    for (int p = tid; p < N_; p += 256) {
        float v0 = xb[p * 3 + 0], v1 = xb[p * 3 + 1], v2 = xb[p * 3 + 2];
        float sq = __fadd_rn(__fadd_rn(__fmul_rn(v0, v0), __fmul_rn(v1, v1)),
                             __fmul_rn(v2, v2));
        pts[p] = make_float4(v0, v1, v2, sq);
    }
    __syncthreads();

    const int row_l = perm[b * N_ + blockIdx.x * 256 + tid]; // Morton-ordered row
    const float4 xi = pts[row_l];
    const float sqi = xi.w;

    unsigned long long bk[KNN];
#pragma unroll
    for (int k = 0; k < KNN; ++k) bk[k] = ~0ull;
    unsigned long long worst = ~0ull; int wslot = 0;

    auto mkkey = [&](const float4& p, int j) -> unsigned long long {
        float dot = __fadd_rn(__fadd_rn(__fmul_rn(xi.x, p.x),
                                        __fmul_rn(xi.y, p.y)),
                              __fmul_rn(xi.z, p.z));
        float d = __fsub_rn(__fadd_rn(sqi, p.w), __fmul_rn(2.0f, dot));
        unsigned u = __float_as_uint(d);
        unsigned s = u ^ (0x80000000u | (unsigned)((int)u >> 31));
        return ((unsigned long long)s << 32) | (unsigned)j;
    };
    auto insert = [&](unsigned long long key) {
        if (key < worst) {
#pragma unroll
            for (int k = 0; k < KNN; ++k)
                if (k == wslot) bk[k] = key;
            unsigned long long w = 0; int sl = 0;
#pragma unroll
            for (int k = 0; k < KNN; ++k)
                if (bk[k] > w) { w = bk[k]; sl = k; }
            worst = w; wslot = sl;
        }
    };

    for (int j = 0; j < N_; j += 4) {
        float4 p0 = pts[j + 0]; float4 p1 = pts[j + 1];
        float4 p2 = pts[j + 2]; float4 p3 = pts[j + 3];
        unsigned long long k0 = mkkey(p0, j + 0);
        unsigned long long k1 = mkkey(p1, j + 1);
        unsigned long long k2 = mkkey(p2, j + 2);
        unsigned long long k3 = mkkey(p3, j + 3);
        // group check vs stale worst: over-enters only (worst monotone down)
        if ((k0 < worst) | (k1 < worst) | (k2 < worst) | (k3 < worst)) {
            insert(k0); insert(k1); insert(k2); insert(k3);
        }
    }

    const long long row = (long long)b * N_ + row_l;
    int bi[KNN];
#pragma unroll
    for (int k = 0; k < KNN; ++k) bi[k] = (int)(bk[k] & 0xFFFFFFFFull);
#pragma unroll
    for (int k = 0; k < KNN; ++k) idx_out[row * KNN + k] = bi[k];

    // --- BN statistics: Sum e (6) and Sum e e^T (upper triangle, 21) ---
    float acc[27];
#pragma unroll
    for (int t = 0; t < 27; ++t) acc[t] = 0.0f;
#pragma unroll
    for (int k = 0; k < KNN; ++k) {
        float4 pj = pts[bi[k]];
        float e[6] = { xi.x, xi.y, xi.z,
                       pj.x - xi.x, pj.y - xi.y, pj.z - xi.z };
        int t = 6;
#pragma unroll
        for (int a = 0; a < 6; ++a) {
            acc[a] += e[a];
#pragma unroll
            for (int bb = a; bb < 6; ++bb) acc[t++] += e[a] * e[bb];
        }
    }
#pragma unroll
    for (int t = 0; t < 27; ++t) {
        float v = acc[t];
        v += __shfl_down(v, 32); v += __shfl_down(v, 16);
        v += __shfl_down(v, 8);  v += __shfl_down(v, 4);
        v += __shfl_down(v, 2);  v += __shfl_down(v, 1);
        acc[t] = v;
    }
    if ((tid & 63) == 0) {
#pragma unroll
        for (int t = 0; t < 27; ++t) atomicAdd(&stats[t], (double)acc[t]);
    }
}

// ===========================================================================
// Kernel 2: fold stats -> per-channel scale/shift (fp64, 64 threads)
// ===========================================================================
__global__ void bn_prep_kernel(
    const double* __restrict__ stats,
    const float* __restrict__ w1, const float* __restrict__ b1,
    const float* __restrict__ gamma, const float* __restrict__ beta,
    float* __restrict__ scale_shift)
{
    const int c = threadIdx.x;
    double s[6], S[6][6];
#pragma unroll
    for (int a = 0; a < 6; ++a) s[a] = stats[a];
    int t = 6;
#pragma unroll
    for (int a = 0; a < 6; ++a)
#pragma unroll
        for (int bb = a; bb < 6; ++bb) { S[a][bb] = stats[t]; S[bb][a] = stats[t]; ++t; }

    const double M = (double)B_ * N_ * KNN;
    double wc[6];
#pragma unroll
    for (int j = 0; j < 6; ++j) wc[j] = (double)w1[j * COUT + c];
    const double b1c = (double)b1[c];

    double sw = 0.0;
#pragma unroll
    for (int j = 0; j < 6; ++j) sw += s[j] * wc[j];
    double mean = sw / M + b1c;

    double q = 0.0;
#pragma unroll
    for (int a = 0; a < 6; ++a)
#pragma unroll
        for (int bb = 0; bb < 6; ++bb) q += S[a][bb] * wc[a] * wc[bb];
    double ex2 = (q + 2.0 * b1c * sw) / M + b1c * b1c;
    double var = ex2 - mean * mean;

    double sc = (double)gamma[c] / sqrt(var + (double)EPS_);
    double sh = (double)beta[c] - mean * sc;
    scale_shift[c]        = (float)sc;
    scale_shift[COUT + c] = (float)sh;
}

// ===========================================================================
// Kernel 3: fused edge-feature -> lin1 -> BN -> ReLU -> lin2 -> max over K
// One wave per point row; lane = output channel. h never hits HBM.
// ===========================================================================
__global__ __launch_bounds__(256) void mlp_max_kernel(
    const float* __restrict__ x, const int* __restrict__ idx,
    const float* __restrict__ w1, const float* __restrict__ b1,
    const float* __restrict__ scale_shift,
    const float* __restrict__ w2, const float* __restrict__ b2,
    float* __restrict__ out)
{
    __shared__ __align__(16) float h1[4][KNN * COUT];   // 20 KB

    const int tid = threadIdx.x;
    const int wv  = tid >> 6;
    const int c   = tid & 63;
    const int row = blockIdx.x * 4 + wv;                // 0 .. B*N-1
    const int b   = row >> 12;

    float w1c[6];
#pragma unroll
    for (int j = 0; j < 6; ++j) w1c[j] = w1[j * COUT + c];
    const float b1c = b1[c];
    const float sc  = scale_shift[c];
    const float sh  = scale_shift[COUT + c];
    const float b2c = b2[c];
    float w2c[COUT];
#pragma unroll
    for (int d = 0; d < COUT; ++d) w2c[d] = w2[d * COUT + c];

    const float xi0 = x[row * 3 + 0];
    const float xi1 = x[row * 3 + 1];
    const float xi2 = x[row * 3 + 2];

    // phase 1: h1[k][c] = relu(scale*(e . w1col_c + b1_c) + shift)
#pragma unroll
    for (int k = 0; k < KNN; ++k) {
        int j = idx[row * KNN + k];                     // wave-uniform load
        const float* pj = x + ((size_t)b * N_ + j) * 3;
        float e3 = pj[0] - xi0, e4 = pj[1] - xi1, e5 = pj[2] - xi2;
        float h = b1c;
        h = fmaf(xi0, w1c[0], h); h = fmaf(xi1, w1c[1], h);
        h = fmaf(xi2, w1c[2], h); h = fmaf(e3,  w1c[3], h);
        h = fmaf(e4,  w1c[4], h); h = fmaf(e5,  w1c[5], h);
        h = fmaf(h, sc, sh);
        h1[wv][k * COUT + c] = fmaxf(h, 0.0f);
    }
    __syncthreads();

    // phase 2: out[c] = max_k ( h1[k][:] . w2col_c + b2_c )
    float mx = -INFINITY;
    for (int k = 0; k < KNN; ++k) {
        float a = b2c;
#pragma unroll
        for (int d4 = 0; d4 < COUT / 4; ++d4) {
            float4 hv = *(const float4*)&h1[wv][k * COUT + d4 * 4];  // broadcast
            a = fmaf(hv.x, w2c[d4 * 4 + 0], a);
            a = fmaf(hv.y, w2c[d4 * 4 + 1], a);
            a = fmaf(hv.z, w2c[d4 * 4 + 2], a);
            a = fmaf(hv.w, w2c[d4 * 4 + 3], a);
        }
        mx = fmaxf(mx, a);
    }
    out[(size_t)row * COUT + c] = mx;
}

// ===========================================================================
extern "C" void kernel_launch(void* const* d_in, const int* in_sizes, int n_in,
                              void* d_out, int out_size, void* d_ws, size_t ws_size,
                              hipStream_t stream)
{
    const float* x     = (const float*)d_in[0];
    // d_in[1] = batch vector (implied by layout, unused)
    const float* w1    = (const float*)d_in[2];
    const float* b1    = (const float*)d_in[3];
    const float* gamma = (const float*)d_in[4];
    const float* beta  = (const float*)d_in[5];
    const float* w2    = (const float*)d_in[6];
    const float* b2    = (const float*)d_in[7];
    float* out = (float*)d_out;

    char*   ws          = (char*)d_ws;
    double* stats       = (double*)ws;
    float*  scale_shift = (float*)(ws + 256);
    int*    idx         = (int*)(ws + 1024);
    int*    perm        = (int*)(ws + 1024 + (size_t)B_ * N_ * KNN * 4);

    hipMemsetAsync(stats, 0, 27 * sizeof(double), stream);
    morton_sort_kernel<<<B_, 1024, 0, stream>>>(x, perm);
    knn_stats_kernel<<<dim3(16, 16), 256, 0, stream>>>(x, perm, idx, stats);
    bn_prep_kernel<<<1, COUT, 0, stream>>>(stats, w1, b1, gamma, beta, scale_shift);
    mlp_max_kernel<<<(B_ * N_) / 4, 256, 0, stream>>>(x, idx, w1, b1, scale_shift,
                                                      w2, b2, out);
}

// Round 5
// 1011.784 us; speedup vs baseline: 2.9267x; 1.1210x over previous
//
#include <hip/hip_runtime.h>
#include <math.h>
#include <float.h>

#define B_   16
#define N_   4096
#define CIN  3
#define COUT 64
#define KNN  20
#define EPS_ 1e-5

// ---------------------------------------------------------------------------
// Workspace layout:
//   [0,   216): double stats[27]    (Sum e[6], Sum e e^T upper-tri[21])
//   [256, 768): float scale[64], shift[64]
//   [1024, 1024 + B*N*KNN*4): int idx[B*N*KNN]           (5242880 B)
//   [5243904, +B*N*4): int perm[B*N]  (Morton row order)  (262144 B)
// ---------------------------------------------------------------------------

__device__ __forceinline__ unsigned expand10(unsigned v) {
    v = (v | (v << 16)) & 0x030000FFu;
    v = (v | (v << 8))  & 0x0300F00Fu;
    v = (v | (v << 4))  & 0x030C30C3u;
    v = (v | (v << 2))  & 0x09249249u;
    return v;
}
__device__ __forceinline__ unsigned quant10(float v) {
    int q = (int)((v + 4.0f) * 128.0f);
    return (unsigned)min(1023, max(0, q));
}

// ===========================================================================
// Kernel 0: per-batch Morton COUNTING sort (1024 buckets = top 10 morton
// bits). Replaces the 78-barrier-phase bitonic (round 4). PERFORMANCE ONLY:
// any permutation is correctness-neutral; within-bucket order (atomic order)
// is arbitrary and only perturbs fp32 stats summation order (~1e-6).
// ===========================================================================
__global__ __launch_bounds__(1024) void morton_bucket_kernel(
    const float* __restrict__ x, int* __restrict__ perm)
{
    __shared__ int hist[1024];
    __shared__ int scanbuf[1024];
    __shared__ int offs[1024];
    const int b = blockIdx.x, tid = threadIdx.x;
    const float* xb = x + (size_t)b * N_ * CIN;

    hist[tid] = 0;
    __syncthreads();

    int keys[4];
#pragma unroll
    for (int i = 0; i < 4; ++i) {
        int p = tid + i * 1024;
        float v0 = xb[p * 3 + 0], v1 = xb[p * 3 + 1], v2 = xb[p * 3 + 2];
        unsigned m = (expand10(quant10(v0)) << 2) |
                     (expand10(quant10(v1)) << 1) |
                      expand10(quant10(v2));
        keys[i] = (int)(m >> 20);          // top 10 bits
        atomicAdd(&hist[keys[i]], 1);
    }
    __syncthreads();

    int v = hist[tid];
    scanbuf[tid] = v;
    __syncthreads();
    for (int off = 1; off < 1024; off <<= 1) {   // Hillis-Steele inclusive
        int t = (tid >= off) ? scanbuf[tid - off] : 0;
        __syncthreads();
        scanbuf[tid] += t;
        __syncthreads();
    }
    offs[tid] = scanbuf[tid] - v;                // exclusive base
    __syncthreads();

#pragma unroll
    for (int i = 0; i < 4; ++i) {
        int p = tid + i * 1024;
        int pos = atomicAdd(&offs[keys[i]], 1);
        perm[b * N_ + pos] = p;
    }
}

// ===========================================================================
// Kernel 1: exact-match KNN (top-20, jax top_k semantics) + BN stats.
// Distance: fp32 EXPANSION form, bit-identical to np ref (verified round 3).
// Selection: 20 smallest u64 keys (sortable_fp32(d)<<32 | j) — exact top_k
// with lowest-index tie-break; quartering the candidate set + merging is
// semantics-preserving (20 smallest of the union).
//
// Structure (round 5): 512 threads = 8 waves = 2 row-groups x 4 quarter
// waves; full batch staged in 64KB LDS; each wave scans 1024 candidates
// (heap prefilled with the quarter's first 20); 2-round LDS tree merge
// (q0<-q1, q2<-q3, q0<-q2) reusing the pts buffer as scratch. Grid 512
// blocks -> 2 blocks/CU -> 16 waves/CU (vs 4 in round 4): hides the stalls
// that capped VALUBusy at 27%.
// ===========================================================================
__global__ __launch_bounds__(512) void knn_quarter_kernel(
    const float* __restrict__ x, const int* __restrict__ perm,
    int* __restrict__ idx_out, double* __restrict__ stats)
{
    __shared__ __align__(16) char smem[65536];
    float4* pts = (float4*)smem;                       // staging view
    unsigned long long* scr = (unsigned long long*)smem; // merge-scratch view

    const int b    = blockIdx.y;
    const int tid  = threadIdx.x;
    const int wave = tid >> 6;
    const int lane = tid & 63;
    const int r    = wave >> 2;     // row-group 0..1
    const int q    = wave & 3;      // candidate quarter
    const float* xb = x + (size_t)b * N_ * CIN;

    for (int p = tid; p < N_; p += 512) {
        float v0 = xb[p * 3 + 0], v1 = xb[p * 3 + 1], v2 = xb[p * 3 + 2];
        float sq = __fadd_rn(__fadd_rn(__fmul_rn(v0, v0), __fmul_rn(v1, v1)),
                             __fmul_rn(v2, v2));
        pts[p] = make_float4(v0, v1, v2, sq);
    }
    __syncthreads();

    const int row_l = perm[b * N_ + blockIdx.x * 128 + r * 64 + lane];
    const float4 xi = pts[row_l];
    const float sqi = xi.w;

    auto mkkey = [&](const float4& p, int j) -> unsigned long long {
        float dot = __fadd_rn(__fadd_rn(__fmul_rn(xi.x, p.x),
                                        __fmul_rn(xi.y, p.y)),
                              __fmul_rn(xi.z, p.z));
        float d = __fsub_rn(__fadd_rn(sqi, p.w), __fmul_rn(2.0f, dot));
        unsigned u = __float_as_uint(d);
        unsigned s = u ^ (0x80000000u | (unsigned)((int)u >> 31));
        return ((unsigned long long)s << 32) | (unsigned)j;
    };

    unsigned long long bk[KNN];
    unsigned long long worst; int wslot;

    // prefill heap with the quarter's first 20 candidates (no rescans)
    const int jbase = q * 1024;
#pragma unroll
    for (int k = 0; k < KNN; ++k) bk[k] = mkkey(pts[jbase + k], jbase + k);
    {
        unsigned long long w = 0; int sl = 0;
#pragma unroll
        for (int k = 0; k < KNN; ++k)
            if (bk[k] > w) { w = bk[k]; sl = k; }
        worst = w; wslot = sl;
    }

    auto insert = [&](unsigned long long key) {
        if (key < worst) {
#pragma unroll
            for (int k = 0; k < KNN; ++k)
                if (k == wslot) bk[k] = key;
            unsigned long long w = 0; int sl = 0;
#pragma unroll
            for (int k = 0; k < KNN; ++k)
                if (bk[k] > w) { w = bk[k]; sl = k; }
            worst = w; wslot = sl;
        }
    };

    for (int jj = 20; jj < 1024; jj += 4) {
        int j = jbase + jj;
        float4 p0 = pts[j + 0]; float4 p1 = pts[j + 1];
        float4 p2 = pts[j + 2]; float4 p3 = pts[j + 3];
        unsigned long long k0 = mkkey(p0, j + 0);
        unsigned long long k1 = mkkey(p1, j + 1);
        unsigned long long k2 = mkkey(p2, j + 2);
        unsigned long long k3 = mkkey(p3, j + 3);
        if ((k0 < worst) | (k1 < worst) | (k2 < worst) | (k3 < worst)) {
            insert(k0); insert(k1); insert(k2); insert(k3);
        }
    }
    __syncthreads();    // scans done; pts dead (xi in regs) -> scr valid

    // merge round A: q1 -> slot0, q3 -> slot1   (2*2*64*20*8B = 40KB <= 64KB)
    if (q & 1) {
        int base = ((r * 2 + (q >> 1)) * 64 + lane) * KNN;
#pragma unroll
        for (int k = 0; k < KNN; ++k) scr[base + k] = bk[k];
    }
    __syncthreads();
    if (!(q & 1)) {                 // q0 absorbs q1; q2 absorbs q3
        int base = ((r * 2 + (q >> 1)) * 64 + lane) * KNN;
#pragma unroll
        for (int k = 0; k < KNN; ++k) insert(scr[base + k]);
    }
    __syncthreads();
    // merge round B: q2 -> slot1; q0 absorbs
    if (q == 2) {
        int base = ((r * 2 + 1) * 64 + lane) * KNN;
#pragma unroll
        for (int k = 0; k < KNN; ++k) scr[base + k] = bk[k];
    }
    __syncthreads();
    if (q == 0) {
        int base = ((r * 2 + 1) * 64 + lane) * KNN;
#pragma unroll
        for (int k = 0; k < KNN; ++k) insert(scr[base + k]);

        const long long row = (long long)b * N_ + row_l;
        int bi[KNN];
#pragma unroll
        for (int k = 0; k < KNN; ++k) bi[k] = (int)(bk[k] & 0xFFFFFFFFull);
#pragma unroll
        for (int k = 0; k < KNN; ++k) idx_out[row * KNN + k] = bi[k];

        // --- BN statistics (neighbor coords from global; batch slab is hot)
        float acc[27];
#pragma unroll
        for (int t = 0; t < 27; ++t) acc[t] = 0.0f;
#pragma unroll
        for (int k = 0; k < KNN; ++k) {
            const float* pj = xb + bi[k] * 3;
            float e[6] = { xi.x, xi.y, xi.z,
                           pj[0] - xi.x, pj[1] - xi.y, pj[2] - xi.z };
            int t = 6;
#pragma unroll
            for (int a = 0; a < 6; ++a) {
                acc[a] += e[a];
#pragma unroll
                for (int bb = a; bb < 6; ++bb) acc[t++] += e[a] * e[bb];
            }
        }
#pragma unroll
        for (int t = 0; t < 27; ++t) {
            float v = acc[t];
            v += __shfl_down(v, 32); v += __shfl_down(v, 16);
            v += __shfl_down(v, 8);  v += __shfl_down(v, 4);
            v += __shfl_down(v, 2);  v += __shfl_down(v, 1);
            acc[t] = v;
        }
        if (lane == 0) {
#pragma unroll
            for (int t = 0; t < 27; ++t) atomicAdd(&stats[t], (double)acc[t]);
        }
    }
}

// ===========================================================================
// Kernel 2: fold stats -> per-channel scale/shift (fp64, 64 threads)
// ===========================================================================
__global__ void bn_prep_kernel(
    const double* __restrict__ stats,
    const float* __restrict__ w1, const float* __restrict__ b1,
    const float* __restrict__ gamma, const float* __restrict__ beta,
    float* __restrict__ scale_shift)
{
    const int c = threadIdx.x;
    double s[6], S[6][6];
#pragma unroll
    for (int a = 0; a < 6; ++a) s[a] = stats[a];
    int t = 6;
#pragma unroll
    for (int a = 0; a < 6; ++a)
#pragma unroll
        for (int bb = a; bb < 6; ++bb) { S[a][bb] = stats[t]; S[bb][a] = stats[t]; ++t; }

    const double M = (double)B_ * N_ * KNN;
    double wc[6];
#pragma unroll
    for (int j = 0; j < 6; ++j) wc[j] = (double)w1[j * COUT + c];
    const double b1c = (double)b1[c];

    double sw = 0.0;
#pragma unroll
    for (int j = 0; j < 6; ++j) sw += s[j] * wc[j];
    double mean = sw / M + b1c;

    double qq = 0.0;
#pragma unroll
    for (int a = 0; a < 6; ++a)
#pragma unroll
        for (int bb = 0; bb < 6; ++bb) qq += S[a][bb] * wc[a] * wc[bb];
    double ex2 = (qq + 2.0 * b1c * sw) / M + b1c * b1c;
    double var = ex2 - mean * mean;

    double sc = (double)gamma[c] / sqrt(var + (double)EPS_);
    double sh = (double)beta[c] - mean * sc;
    scale_shift[c]        = (float)sc;
    scale_shift[COUT + c] = (float)sh;
}

// ===========================================================================
// Kernel 3: fused edge-feature -> lin1 -> BN -> ReLU -> lin2 -> max over K.
// Round 5: 8 rows per wave (weight registers amortized 8x), rows processed
// in pairs packed [k][d][pair] in LDS so phase-2 float4 reads feed 2 rows.
// ===========================================================================
__global__ __launch_bounds__(256) void mlp_max_kernel(
    const float* __restrict__ x, const int* __restrict__ idx,
    const float* __restrict__ w1, const float* __restrict__ b1,
    const float* __restrict__ scale_shift,
    const float* __restrict__ w2, const float* __restrict__ b2,
    float* __restrict__ out)
{
    __shared__ __align__(16) float h2[4][KNN][COUT][2];   // 40 KB

    const int tid = threadIdx.x;
    const int wv  = tid >> 6;
    const int c   = tid & 63;

    float w1c[6];
#pragma unroll
    for (int j = 0; j < 6; ++j) w1c[j] = w1[j * COUT + c];
    const float b1c = b1[c];
    const float sc  = scale_shift[c];
    const float sh  = scale_shift[COUT + c];
    const float b2c = b2[c];
    float w2c[COUT];
#pragma unroll
    for (int d = 0; d < COUT; ++d) w2c[d] = w2[d * COUT + c];

    const int rowbase = (blockIdx.x * 4 + wv) * 8;

    for (int pair = 0; pair < 4; ++pair) {
        const int ra = rowbase + pair * 2;
#pragma unroll
        for (int rr = 0; rr < 2; ++rr) {
            const int row = ra + rr;
            const int b   = row >> 12;
            const float xi0 = x[row * 3 + 0];
            const float xi1 = x[row * 3 + 1];
            const float xi2 = x[row * 3 + 2];
#pragma unroll
            for (int k = 0; k < KNN; ++k) {
                int j = idx[row * KNN + k];               // wave-uniform
                const float* pj = x + ((size_t)b * N_ + j) * 3;
                float e3 = pj[0] - xi0, e4 = pj[1] - xi1, e5 = pj[2] - xi2;
                float h = b1c;
                h = fmaf(xi0, w1c[0], h); h = fmaf(xi1, w1c[1], h);
                h = fmaf(xi2, w1c[2], h); h = fmaf(e3,  w1c[3], h);
                h = fmaf(e4,  w1c[4], h); h = fmaf(e5,  w1c[5], h);
                h = fmaf(h, sc, sh);
                h2[wv][k][c][rr] = fmaxf(h, 0.0f);        // 2-way bank alias: free
            }
        }
        __syncthreads();   // uniform across the block's 4 waves

        float mxa = -INFINITY, mxb = -INFINITY;
        for (int k = 0; k < KNN; ++k) {
            float aa = b2c, ab = b2c;
#pragma unroll
            for (int d2 = 0; d2 < COUT / 2; ++d2) {
                float4 hv = *(const float4*)&h2[wv][k][d2 * 2][0]; // broadcast
                aa = fmaf(hv.x, w2c[d2 * 2 + 0], aa);
                ab = fmaf(hv.y, w2c[d2 * 2 + 0], ab);
                aa = fmaf(hv.z, w2c[d2 * 2 + 1], aa);
                ab = fmaf(hv.w, w2c[d2 * 2 + 1], ab);
            }
            mxa = fmaxf(mxa, aa); mxb = fmaxf(mxb, ab);
        }
        out[(size_t)ra * COUT + c]       = mxa;
        out[(size_t)(ra + 1) * COUT + c] = mxb;
        __syncthreads();   // protect h2 reuse next pair
    }
}

// ===========================================================================
extern "C" void kernel_launch(void* const* d_in, const int* in_sizes, int n_in,
                              void* d_out, int out_size, void* d_ws, size_t ws_size,
                              hipStream_t stream)
{
    const float* x     = (const float*)d_in[0];
    const float* w1    = (const float*)d_in[2];
    const float* b1    = (const float*)d_in[3];
    const float* gamma = (const float*)d_in[4];
    const float* beta  = (const float*)d_in[5];
    const float* w2    = (const float*)d_in[6];
    const float* b2    = (const float*)d_in[7];
    float* out = (float*)d_out;

    char*   ws          = (char*)d_ws;
    double* stats       = (double*)ws;
    float*  scale_shift = (float*)(ws + 256);
    int*    idx         = (int*)(ws + 1024);
    int*    perm        = (int*)(ws + 1024 + (size_t)B_ * N_ * KNN * 4);

    hipMemsetAsync(stats, 0, 27 * sizeof(double), stream);
    morton_bucket_kernel<<<B_, 1024, 0, stream>>>(x, perm);
    knn_quarter_kernel<<<dim3(32, 16), 512, 0, stream>>>(x, perm, idx, stats);
    bn_prep_kernel<<<1, COUT, 0, stream>>>(stats, w1, b1, gamma, beta, scale_shift);
    mlp_max_kernel<<<(B_ * N_) / 32, 256, 0, stream>>>(x, idx, w1, b1, scale_shift,
                                                       w2, b2, out);
}